// Round 6
// baseline (538.481 us; speedup 1.0000x reference)
//
#include <hip/hip_runtime.h>
#include <hip/hip_bf16.h>
#include <hip/hip_cooperative_groups.h>

namespace cg = cooperative_groups;

#define S_  2048
#define DM_ 512
#define H_  8
#define DH_ 64
#define MF_ 64
#define DFF_ 2048
#define L_  2
#define CT_ 64
#define NC_ (S_ / CT_)
#define EPS_ 1e-6f
#define LN_EPS_ 1e-5f

#define LSW_   3145728
#define W1OFF_ 1048576
#define W2OFF_ 2097152
#define WOOFF_ 786432

typedef unsigned short ushortT;
typedef unsigned int u32;
typedef float f4 __attribute__((ext_vector_type(4)));
typedef short s8 __attribute__((ext_vector_type(8)));
typedef u32 u32x2 __attribute__((ext_vector_type(2)));

__device__ __forceinline__ ushortT f2b(float f) {
  union { float f; unsigned u; } v; v.f = f;
  unsigned r = v.u + 0x7fffu + ((v.u >> 16) & 1u);  // RNE
  return (ushortT)(r >> 16);
}
__device__ __forceinline__ float bu2f(ushortT h) {
  union { unsigned u; float f; } v; v.u = ((unsigned)h) << 16; return v.f;
}
__device__ __forceinline__ u32 pk2(float a, float b) {
  return (u32)f2b(a) | ((u32)f2b(b) << 16);
}

// ---------------------------------------------------------------- fused setup
// flat grid: [0,2048) QKVO transpose, [2048,4096) W1, [4096,6144) W2,
// [6144,6152) omega, [6152,10248) copy_in
__global__ __launch_bounds__(256) void tcast_all(
    const float* __restrict__ x,
    const float* __restrict__ Wq, const float* __restrict__ Wk,
    const float* __restrict__ Wv, const float* __restrict__ Wo,
    const float* __restrict__ W1, const float* __restrict__ W2,
    const float* __restrict__ omg,
    float* __restrict__ cur, ushortT* __restrict__ curb,
    ushortT* __restrict__ wb, ushortT* __restrict__ omgTb) {
  const int bid = blockIdx.x;
  const int t = threadIdx.x;
  if (bid >= 6152) {  // copy_in
    const int i = (bid - 6152) * 256 + t;
    float v = x[i];
    cur[i] = v;
    curb[i] = f2b(v);
    return;
  }
  __shared__ ushortT tile[32][33];
  const float* src; ushortT* dst; int K, N, bx, by;
  if (bid < 2048) {
    const int z = bid >> 8, widx = z & 3, lay = z >> 2;
    const float* s4[4] = {Wq, Wk, Wv, Wo};
    src = s4[widx] + (size_t)lay * DM_ * DM_;
    dst = wb + (size_t)lay * LSW_ + (size_t)widx * DM_ * DM_;
    K = DM_; N = DM_; bx = bid & 15; by = (bid >> 4) & 15;
  } else if (bid < 4096) {
    const int r = bid - 2048;
    const int lay = r >> 10;
    src = W1 + (size_t)lay * DM_ * DFF_;
    dst = wb + (size_t)lay * LSW_ + W1OFF_;
    K = DM_; N = DFF_; bx = r & 63; by = (r >> 6) & 15;
  } else if (bid < 6144) {
    const int r = bid - 4096;
    const int lay = r >> 10;
    src = W2 + (size_t)lay * DFF_ * DM_;
    dst = wb + (size_t)lay * LSW_ + W2OFF_;
    K = DFF_; N = DM_; bx = r & 15; by = (r >> 4) & 63;
  } else {
    const int r = bid - 6144;
    const int lay = r >> 2;
    src = omg + (size_t)lay * DH_ * MF_;
    dst = omgTb + (size_t)lay * DH_ * MF_;
    K = DH_; N = MF_; bx = r & 1; by = (r >> 1) & 1;
  }
  const int cc = t & 31, r0 = t >> 5;
  const int n0 = bx * 32, k0 = by * 32;
#pragma unroll
  for (int i = 0; i < 4; ++i) {
    int r = r0 + 8 * i;
    tile[r][cc] = f2b(src[(size_t)(k0 + r) * N + n0 + cc]);
  }
  __syncthreads();
#pragma unroll
  for (int i = 0; i < 4; ++i) {
    int r = r0 + 8 * i;
    dst[(size_t)(n0 + r) * K + k0 + cc] = tile[cc][r];
  }
}

// ---------------------------------------------------------------- MFMA GEMM (full-K)
template<bool RELU, bool HAS_RES, bool OUT_BF16>
__global__ __launch_bounds__(256) void mgemm(
    const ushortT* __restrict__ A, const ushortT* __restrict__ Wt,
    const float* __restrict__ bq_, const float* __restrict__ bk_,
    const float* __restrict__ bv_, const float* __restrict__ Res,
    float* __restrict__ Cf, ushortT* __restrict__ Cb, int K, int N) {
  __shared__ ushortT sA[2][2048];
  __shared__ ushortT sB[2][2048];
  const int t = threadIdx.x;
  const int w = t >> 6, l = t & 63;
  const int wm = w >> 1, wn = w & 1;
  const int n0 = blockIdx.x * 64, m0 = blockIdx.y * 64;
  const int z = blockIdx.z;
  const ushortT* Wz = Wt + (size_t)z * K * N;
  const float* bias = (z == 0) ? bq_ : (z == 1 ? bk_ : bv_);

  const int rs = w * 16 + (l >> 2);
  const int qs = (l & 3) ^ ((rs >> 1) & 3);
  const ushortT* gA = A  + (size_t)(m0 + rs) * K + qs * 8;
  const ushortT* gB = Wz + (size_t)(n0 + rs) * K + qs * 8;

  const int Ra = wm * 32 + (l & 15);
  const int Rb = wn * 32 + (l & 15);
  const int qq = l >> 4;
  const int aoff = (Ra * 4 + (qq ^ ((Ra >> 1) & 3))) * 8;
  const int boff = (Rb * 4 + (qq ^ ((Rb >> 1) & 3))) * 8;

  f4 acc[2][2];
#pragma unroll
  for (int i = 0; i < 2; ++i)
#pragma unroll
    for (int j = 0; j < 2; ++j) acc[i][j] = (f4){0.f, 0.f, 0.f, 0.f};

  auto stage = [&](int buf, int ko) {
    __builtin_amdgcn_global_load_lds(
        (const __attribute__((address_space(1))) void*)(gA + ko),
        (__attribute__((address_space(3))) void*)(&sA[buf][w * 512]), 16, 0, 0);
    __builtin_amdgcn_global_load_lds(
        (const __attribute__((address_space(1))) void*)(gB + ko),
        (__attribute__((address_space(3))) void*)(&sB[buf][w * 512]), 16, 0, 0);
  };

  stage(0, 0);
  const int nk = K >> 5;
  for (int ks = 0; ks < nk; ++ks) {
    __syncthreads();
    if (ks + 1 < nk) stage((ks + 1) & 1, (ks + 1) * 32);
    const ushortT* pa = sA[ks & 1];
    const ushortT* pb = sB[ks & 1];
    s8 a0 = *(const s8*)(pa + aoff);
    s8 a1 = *(const s8*)(pa + aoff + 512);
    s8 b0 = *(const s8*)(pb + boff);
    s8 b1 = *(const s8*)(pb + boff + 512);
    acc[0][0] = __builtin_amdgcn_mfma_f32_16x16x32_bf16(a0, b0, acc[0][0], 0, 0, 0);
    acc[0][1] = __builtin_amdgcn_mfma_f32_16x16x32_bf16(a0, b1, acc[0][1], 0, 0, 0);
    acc[1][0] = __builtin_amdgcn_mfma_f32_16x16x32_bf16(a1, b0, acc[1][0], 0, 0, 0);
    acc[1][1] = __builtin_amdgcn_mfma_f32_16x16x32_bf16(a1, b1, acc[1][1], 0, 0, 0);
  }

  const size_t outz = (size_t)z * S_ * N;
  const int colb = n0 + wn * 32 + (l & 15);
  const int rowb = m0 + wm * 32 + ((l >> 4) << 2);
#pragma unroll
  for (int mt = 0; mt < 2; ++mt) {
#pragma unroll
    for (int nt = 0; nt < 2; ++nt) {
      const int c = colb + nt * 16;
      const float bv = bias[c];
#pragma unroll
      for (int r = 0; r < 4; ++r) {
        const int rr = rowb + mt * 16 + r;
        float v = acc[mt][nt][r] + bv;
        if (HAS_RES) v += Res[(size_t)rr * N + c];
        if (RELU) v = fmaxf(v, 0.f);
        if (OUT_BF16) Cb[outz + (size_t)rr * N + c] = f2b(v);
        else          Cf[outz + (size_t)rr * N + c] = v;
      }
    }
  }
}

// ---------------------------------------------------------------- MFMA GEMM partial (split-K)
__global__ __launch_bounds__(256) void mgemm_part(
    const ushortT* __restrict__ A, const ushortT* __restrict__ Wt,
    float* __restrict__ PS, int K, int N, int KS) {
  __shared__ ushortT sA[2][2048];
  __shared__ ushortT sB[2][2048];
  const int t = threadIdx.x;
  const int w = t >> 6, l = t & 63;
  const int wm = w >> 1, wn = w & 1;
  const int n0 = blockIdx.x * 64, m0 = blockIdx.y * 64;
  const int z = blockIdx.z;

  const int rs = w * 16 + (l >> 2);
  const int qs = (l & 3) ^ ((rs >> 1) & 3);
  const ushortT* gA = A  + (size_t)(m0 + rs) * K + z * KS + qs * 8;
  const ushortT* gB = Wt + (size_t)(n0 + rs) * K + z * KS + qs * 8;

  const int Ra = wm * 32 + (l & 15);
  const int Rb = wn * 32 + (l & 15);
  const int qq = l >> 4;
  const int aoff = (Ra * 4 + (qq ^ ((Ra >> 1) & 3))) * 8;
  const int boff = (Rb * 4 + (qq ^ ((Rb >> 1) & 3))) * 8;

  f4 acc[2][2];
#pragma unroll
  for (int i = 0; i < 2; ++i)
#pragma unroll
    for (int j = 0; j < 2; ++j) acc[i][j] = (f4){0.f, 0.f, 0.f, 0.f};

  auto stage = [&](int buf, int ko) {
    __builtin_amdgcn_global_load_lds(
        (const __attribute__((address_space(1))) void*)(gA + ko),
        (__attribute__((address_space(3))) void*)(&sA[buf][w * 512]), 16, 0, 0);
    __builtin_amdgcn_global_load_lds(
        (const __attribute__((address_space(1))) void*)(gB + ko),
        (__attribute__((address_space(3))) void*)(&sB[buf][w * 512]), 16, 0, 0);
  };

  stage(0, 0);
  const int nk = KS >> 5;
  for (int ks = 0; ks < nk; ++ks) {
    __syncthreads();
    if (ks + 1 < nk) stage((ks + 1) & 1, (ks + 1) * 32);
    const ushortT* pa = sA[ks & 1];
    const ushortT* pb = sB[ks & 1];
    s8 a0 = *(const s8*)(pa + aoff);
    s8 a1 = *(const s8*)(pa + aoff + 512);
    s8 b0 = *(const s8*)(pb + boff);
    s8 b1 = *(const s8*)(pb + boff + 512);
    acc[0][0] = __builtin_amdgcn_mfma_f32_16x16x32_bf16(a0, b0, acc[0][0], 0, 0, 0);
    acc[0][1] = __builtin_amdgcn_mfma_f32_16x16x32_bf16(a0, b1, acc[0][1], 0, 0, 0);
    acc[1][0] = __builtin_amdgcn_mfma_f32_16x16x32_bf16(a1, b0, acc[1][0], 0, 0, 0);
    acc[1][1] = __builtin_amdgcn_mfma_f32_16x16x32_bf16(a1, b1, acc[1][1], 0, 0, 0);
  }

  float* out = PS + (size_t)z * S_ * N;
  const int colb = n0 + wn * 32 + (l & 15);
  const int rowb = m0 + wm * 32 + ((l >> 4) << 2);
#pragma unroll
  for (int mt = 0; mt < 2; ++mt) {
#pragma unroll
    for (int nt = 0; nt < 2; ++nt) {
      const int c = colb + nt * 16;
#pragma unroll
      for (int r = 0; r < 4; ++r)
        out[(size_t)(rowb + mt * 16 + r) * N + c] = acc[mt][nt][r];
    }
  }
}

// ---------------------------------------------------------------- reduce splits + bias + res + LN
__global__ __launch_bounds__(256) void redln(const float* __restrict__ PS, int nsplit,
                                             const float* __restrict__ bias,
                                             const float* __restrict__ res,
                                             const float* __restrict__ g,
                                             const float* __restrict__ be,
                                             float* __restrict__ outF,
                                             ushortT* __restrict__ outB) {
  const int s = blockIdx.x, t = threadIdx.x;
  float v0 = bias[t] + res[(size_t)s * DM_ + t];
  float v1 = bias[t + 256] + res[(size_t)s * DM_ + 256 + t];
  for (int z = 0; z < nsplit; ++z) {
    const float* p = PS + (size_t)z * S_ * DM_ + (size_t)s * DM_;
    v0 += p[t];
    v1 += p[256 + t];
  }
  float sum = v0 + v1, sq = v0 * v0 + v1 * v1;
  for (int off = 32; off > 0; off >>= 1) {
    sum += __shfl_down(sum, off);
    sq += __shfl_down(sq, off);
  }
  __shared__ float ssum[4], ssq[4];
  __shared__ float smean, srstd;
  const int w = t >> 6;
  if ((t & 63) == 0) { ssum[w] = sum; ssq[w] = sq; }
  __syncthreads();
  if (t == 0) {
    float S1 = ssum[0] + ssum[1] + ssum[2] + ssum[3];
    float S2 = ssq[0] + ssq[1] + ssq[2] + ssq[3];
    float mu = S1 / DM_;
    smean = mu;
    srstd = rsqrtf(S2 / DM_ - mu * mu + LN_EPS_);
  }
  __syncthreads();
  const float mu = smean, rs = srstd;
  float o0 = (v0 - mu) * rs * g[t] + be[t];
  float o1 = (v1 - mu) * rs * g[256 + t] + be[256 + t];
  outF[(size_t)s * DM_ + t] = o0;
  outF[(size_t)s * DM_ + 256 + t] = o1;
  if (outB) {
    outB[(size_t)s * DM_ + t] = f2b(o0);
    outB[(size_t)s * DM_ + 256 + t] = f2b(o1);
  }
}

// ---------------------------------------------------------------- COOPERATIVE fused attention
// Phase A: favor+chunk sums (LDS-resident pq/pk/vT). grid.sync.
// Phase B: exclusive prefix over chunks. grid.sync.
// Phase C: Tm/den/numT, output bf16.
__global__ __launch_bounds__(256) void attn_all(const ushortT* __restrict__ qkv,
                                                const ushortT* __restrict__ omgT,
                                                float* __restrict__ KVcT,
                                                float* __restrict__ Kc,
                                                ushortT* __restrict__ Aout) {
  cg::grid_group grid = cg::this_grid();
  const int bid = blockIdx.x;
  const int c = bid & 31, h = bid >> 5;
  const int t = threadIdx.x;
  const int w = t >> 6, l = t & 63, lr = l & 15, q = l >> 4;

  __shared__ ushortT xq[64 * 72];   // phase C: kvs
  __shared__ ushortT xk[64 * 72];   // phase C: tms
  __shared__ ushortT vT[64 * 72];
  __shared__ ushortT omT[64 * 72];
  __shared__ ushortT pq[64 * 72];
  __shared__ ushortT pk[64 * 72];
  __shared__ ushortT pkT[64 * 72];
  __shared__ float nrm[128];
  __shared__ float den[64];

  // ---------- phase A: load
  const ushortT* qg = qkv + (size_t)(c * CT_) * DM_ + h * DH_;
  const ushortT* kg = qg + (size_t)S_ * DM_;
  const ushortT* vg = kg + (size_t)S_ * DM_;
  for (int i = t; i < 512; i += 256) {
    const int s = i >> 3, seg = i & 7;
    *(s8*)&xq[s * 72 + seg * 8] = *(const s8*)(qg + (size_t)s * DM_ + seg * 8);
    *(s8*)&xk[s * 72 + seg * 8] = *(const s8*)(kg + (size_t)s * DM_ + seg * 8);
    s8 av = *(const s8*)(vg + (size_t)s * DM_ + seg * 8);
#pragma unroll
    for (int j = 0; j < 8; ++j) vT[(seg * 8 + j) * 72 + s] = (ushortT)av[j];
    *(s8*)&omT[s * 72 + seg * 8] = *(const s8*)(omgT + s * 64 + seg * 8);
  }
  __syncthreads();

  if (t < 128) {
    const ushortT* src = (t < 64) ? xq : xk;
    const int s = t & 63;
    float a = 0.f;
#pragma unroll
    for (int seg = 0; seg < 8; ++seg) {
      s8 vv = *(const s8*)(src + s * 72 + seg * 8);
#pragma unroll
      for (int j = 0; j < 8; ++j) {
        float f = bu2f((ushortT)vv[j]);
        a += f * f;
      }
    }
    nrm[t] = a;
  }
  __syncthreads();

  // u = x @ omegaT^T ; phi = exp(gam*u - 0.0625*nrm)*0.125
  {
    const float gam = 0.35355339059327373f;
    const int s0 = w * 16;
    s8 aq0 = *(const s8*)&xq[(s0 + lr) * 72 + q * 8];
    s8 aq1 = *(const s8*)&xq[(s0 + lr) * 72 + 32 + q * 8];
    s8 ak0 = *(const s8*)&xk[(s0 + lr) * 72 + q * 8];
    s8 ak1 = *(const s8*)&xk[(s0 + lr) * 72 + 32 + q * 8];
#pragma unroll
    for (int mt = 0; mt < 4; ++mt) {
      s8 b0 = *(const s8*)&omT[(mt * 16 + lr) * 72 + q * 8];
      s8 b1 = *(const s8*)&omT[(mt * 16 + lr) * 72 + 32 + q * 8];
      f4 cq = (f4){0.f, 0.f, 0.f, 0.f}, ck = (f4){0.f, 0.f, 0.f, 0.f};
      cq = __builtin_amdgcn_mfma_f32_16x16x32_bf16(aq0, b0, cq, 0, 0, 0);
      cq = __builtin_amdgcn_mfma_f32_16x16x32_bf16(aq1, b1, cq, 0, 0, 0);
      ck = __builtin_amdgcn_mfma_f32_16x16x32_bf16(ak0, b0, ck, 0, 0, 0);
      ck = __builtin_amdgcn_mfma_f32_16x16x32_bf16(ak1, b1, ck, 0, 0, 0);
#pragma unroll
      for (int r = 0; r < 4; ++r) {
        const int sr = s0 + q * 4 + r, mc = mt * 16 + lr;
        float vq = expf(gam * cq[r] - 0.0625f * nrm[sr]) * 0.125f;
        float vk = expf(gam * ck[r] - 0.0625f * nrm[64 + sr]) * 0.125f;
        pq[sr * 72 + mc] = f2b(vq);
        ushortT hk = f2b(vk);
        pk[sr * 72 + mc] = hk;
        pkT[mc * 72 + sr] = hk;
      }
    }
  }
  __syncthreads();

  // KVcT[d][m] = V^T @ PK ; Kc[m]
  {
    const int d0 = w * 16;
    s8 a0 = *(const s8*)&vT[(d0 + lr) * 72 + q * 8];
    s8 a1 = *(const s8*)&vT[(d0 + lr) * 72 + 32 + q * 8];
    float* outb = KVcT + (size_t)(h * NC_ + c) * DH_ * MF_;
#pragma unroll
    for (int mt = 0; mt < 4; ++mt) {
      s8 b0 = *(const s8*)&pkT[(mt * 16 + lr) * 72 + q * 8];
      s8 b1 = *(const s8*)&pkT[(mt * 16 + lr) * 72 + 32 + q * 8];
      f4 cc2 = (f4){0.f, 0.f, 0.f, 0.f};
      cc2 = __builtin_amdgcn_mfma_f32_16x16x32_bf16(a0, b0, cc2, 0, 0, 0);
      cc2 = __builtin_amdgcn_mfma_f32_16x16x32_bf16(a1, b1, cc2, 0, 0, 0);
#pragma unroll
      for (int r = 0; r < 4; ++r)
        outb[(size_t)(d0 + q * 4 + r) * MF_ + mt * 16 + lr] = cc2[r];
    }
  }
  if (t < 64) {
    float s = 0.f;
#pragma unroll
    for (int seg = 0; seg < 8; ++seg) {
      s8 vv = *(const s8*)&pkT[t * 72 + seg * 8];
#pragma unroll
      for (int j = 0; j < 8; ++j) s += bu2f((ushortT)vv[j]);
    }
    Kc[(size_t)(h * NC_ + c) * MF_ + t] = s;
  }
  __threadfence();
  grid.sync();

  // ---------- phase B: exclusive prefix over chunks (blocks 0..135)
  if (bid < 128) {
    const int hh = bid >> 4, seg = bid & 15;
    float* base = KVcT + (size_t)hh * NC_ * MF_ * DH_ + seg * 256 + t;
    float v[NC_];
#pragma unroll
    for (int c2 = 0; c2 < NC_; ++c2) v[c2] = base[(size_t)c2 * MF_ * DH_];
    float run = 0.f;
#pragma unroll
    for (int c2 = 0; c2 < NC_; ++c2) {
      float tmp = v[c2];
      base[(size_t)c2 * MF_ * DH_] = run;
      run += tmp;
    }
  } else if (bid < 136 && t < MF_) {
    const int hh = bid - 128;
    float* base = Kc + (size_t)hh * NC_ * MF_ + t;
    float v[NC_];
#pragma unroll
    for (int c2 = 0; c2 < NC_; ++c2) v[c2] = base[(size_t)c2 * MF_];
    float run = 0.f;
#pragma unroll
    for (int c2 = 0; c2 < NC_; ++c2) {
      float tmp = v[c2];
      base[(size_t)c2 * MF_] = run;
      run += tmp;
    }
  }
  __threadfence();
  grid.sync();

  // ---------- phase C
  ushortT* kvs = xq;
  ushortT* tms = xk;
  for (int i = t; i < 512; i += 256) {
    const int s = i >> 3, seg = i & 7;
    const float* kr = KVcT + (size_t)((h * NC_ + c) * DH_ + s) * MF_ + seg * 8;
    f4 g0 = *(const f4*)kr;
    f4 g1 = *(const f4*)(kr + 4);
    u32* p = (u32*)&kvs[s * 72 + seg * 8];
    p[0] = pk2(g0.x, g0.y); p[1] = pk2(g0.z, g0.w);
    p[2] = pk2(g1.x, g1.y); p[3] = pk2(g1.z, g1.w);
  }
  // Tm = PQ @ PK^T, tril (independent of kvs load)
  {
    const int s0 = w * 16;
    s8 a0 = *(const s8*)&pq[(s0 + lr) * 72 + q * 8];
    s8 a1 = *(const s8*)&pq[(s0 + lr) * 72 + 32 + q * 8];
#pragma unroll
    for (int tb = 0; tb < 4; ++tb) {
      f4 cc2 = (f4){0.f, 0.f, 0.f, 0.f};
      if (tb <= w) {
        s8 b0 = *(const s8*)&pk[(tb * 16 + lr) * 72 + q * 8];
        s8 b1 = *(const s8*)&pk[(tb * 16 + lr) * 72 + 32 + q * 8];
        cc2 = __builtin_amdgcn_mfma_f32_16x16x32_bf16(a0, b0, cc2, 0, 0, 0);
        cc2 = __builtin_amdgcn_mfma_f32_16x16x32_bf16(a1, b1, cc2, 0, 0, 0);
      }
#pragma unroll
      for (int r = 0; r < 4; ++r) {
        float v = cc2[r];
        if (tb == w && lr > q * 4 + r) v = 0.f;
        tms[(s0 + q * 4 + r) * 72 + tb * 16 + lr] = f2b(v);
      }
    }
  }
  __syncthreads();

  // den via intra-wave shuffle (4 partials per row are adjacent lanes)
  {
    const int s = t >> 2, part = t & 3;
    float dp = 0.f;
    const u32* trow = (const u32*)&tms[s * 72 + part * 16];
#pragma unroll
    for (int j = 0; j < 8; ++j) {
      u32 u = trow[j];
      dp += bu2f((ushortT)(u & 0xffffu)) + bu2f((ushortT)(u >> 16));
    }
    const u32* qrow = (const u32*)&pq[s * 72 + part * 16];
    const f4* kc4 = (const f4*)(Kc + (size_t)(h * NC_ + c) * MF_ + part * 16);
#pragma unroll
    for (int j = 0; j < 4; ++j) {
      f4 b = kc4[j];
      u32 ua = qrow[2 * j], ub = qrow[2 * j + 1];
      dp += bu2f((ushortT)(ua & 0xffffu)) * b.x + bu2f((ushortT)(ua >> 16)) * b.y +
            bu2f((ushortT)(ub & 0xffffu)) * b.z + bu2f((ushortT)(ub >> 16)) * b.w;
    }
    dp += __shfl_down(dp, 2);
    dp += __shfl_down(dp, 1);
    if (part == 0) den[s] = dp + EPS_;
  }
  __syncthreads();

  // numT + divide + store
  {
    const int d0 = w * 16;
    const int drow = d0 + lr;
    s8 akv0 = *(const s8*)&kvs[drow * 72 + q * 8];
    s8 akv1 = *(const s8*)&kvs[drow * 72 + 32 + q * 8];
    s8 av0  = *(const s8*)&vT[drow * 72 + q * 8];
    s8 av1  = *(const s8*)&vT[drow * 72 + 32 + q * 8];
#pragma unroll
    for (int sb = 0; sb < 4; ++sb) {
      const int srow = sb * 16 + lr;
      s8 bq0 = *(const s8*)&pq[srow * 72 + q * 8];
      s8 bq1 = *(const s8*)&pq[srow * 72 + 32 + q * 8];
      s8 bt0 = *(const s8*)&tms[srow * 72 + q * 8];
      s8 bt1 = *(const s8*)&tms[srow * 72 + 32 + q * 8];
      f4 cc2 = (f4){0.f, 0.f, 0.f, 0.f};
      cc2 = __builtin_amdgcn_mfma_f32_16x16x32_bf16(akv0, bq0, cc2, 0, 0, 0);
      cc2 = __builtin_amdgcn_mfma_f32_16x16x32_bf16(akv1, bq1, cc2, 0, 0, 0);
      cc2 = __builtin_amdgcn_mfma_f32_16x16x32_bf16(av0, bt0, cc2, 0, 0, 0);
      cc2 = __builtin_amdgcn_mfma_f32_16x16x32_bf16(av1, bt1, cc2, 0, 0, 0);
      const float inv = 1.f / den[srow];
      u32x2 o;
      o.x = pk2(cc2[0] * inv, cc2[1] * inv);
      o.y = pk2(cc2[2] * inv, cc2[3] * inv);
      *(u32x2*)(Aout + (size_t)(c * CT_ + srow) * DM_ + h * DH_ + d0 + q * 4) = o;
    }
  }
}

// ---------------------------------------------------------------- FALLBACK kernels (R5 path)
__global__ __launch_bounds__(256) void favor_cs(const ushortT* __restrict__ qkv,
                                                const ushortT* __restrict__ omgT,
                                                ushortT* __restrict__ PQb,
                                                ushortT* __restrict__ PKb,
                                                float* __restrict__ KVcT,
                                                float* __restrict__ Kc) {
  const int c = blockIdx.x, h = blockIdx.y, t = threadIdx.x;
  const int w = t >> 6, l = t & 63, lr = l & 15, q = l >> 4;
  __shared__ ushortT xq[64 * 72], xk[64 * 72], vT[64 * 72], omT[64 * 72];
  __shared__ ushortT pq[64 * 72], pk[64 * 72], pkT[64 * 72];
  __shared__ float nrm[128];

  const ushortT* qg = qkv + (size_t)(c * CT_) * DM_ + h * DH_;
  const ushortT* kg = qg + (size_t)S_ * DM_;
  const ushortT* vg = kg + (size_t)S_ * DM_;

  for (int i = t; i < 512; i += 256) {
    const int s = i >> 3, seg = i & 7;
    *(s8*)&xq[s * 72 + seg * 8] = *(const s8*)(qg + (size_t)s * DM_ + seg * 8);
    *(s8*)&xk[s * 72 + seg * 8] = *(const s8*)(kg + (size_t)s * DM_ + seg * 8);
    s8 av = *(const s8*)(vg + (size_t)s * DM_ + seg * 8);
#pragma unroll
    for (int j = 0; j < 8; ++j) vT[(seg * 8 + j) * 72 + s] = (ushortT)av[j];
    *(s8*)&omT[s * 72 + seg * 8] = *(const s8*)(omgT + s * 64 + seg * 8);
  }
  __syncthreads();

  if (t < 128) {
    const ushortT* src = (t < 64) ? xq : xk;
    const int s = t & 63;
    float a = 0.f;
#pragma unroll
    for (int seg = 0; seg < 8; ++seg) {
      s8 vv = *(const s8*)(src + s * 72 + seg * 8);
#pragma unroll
      for (int j = 0; j < 8; ++j) {
        float f = bu2f((ushortT)vv[j]);
        a += f * f;
      }
    }
    nrm[t] = a;
  }
  __syncthreads();

  {
    const float gam = 0.35355339059327373f;
    const int s0 = w * 16;
    s8 aq0 = *(const s8*)&xq[(s0 + lr) * 72 + q * 8];
    s8 aq1 = *(const s8*)&xq[(s0 + lr) * 72 + 32 + q * 8];
    s8 ak0 = *(const s8*)&xk[(s0 + lr) * 72 + q * 8];
    s8 ak1 = *(const s8*)&xk[(s0 + lr) * 72 + 32 + q * 8];
#pragma unroll
    for (int mt = 0; mt < 4; ++mt) {
      s8 b0 = *(const s8*)&omT[(mt * 16 + lr) * 72 + q * 8];
      s8 b1 = *(const s8*)&omT[(mt * 16 + lr) * 72 + 32 + q * 8];
      f4 cq = (f4){0.f, 0.f, 0.f, 0.f}, ck = (f4){0.f, 0.f, 0.f, 0.f};
      cq = __builtin_amdgcn_mfma_f32_16x16x32_bf16(aq0, b0, cq, 0, 0, 0);
      cq = __builtin_amdgcn_mfma_f32_16x16x32_bf16(aq1, b1, cq, 0, 0, 0);
      ck = __builtin_amdgcn_mfma_f32_16x16x32_bf16(ak0, b0, ck, 0, 0, 0);
      ck = __builtin_amdgcn_mfma_f32_16x16x32_bf16(ak1, b1, ck, 0, 0, 0);
#pragma unroll
      for (int r = 0; r < 4; ++r) {
        const int sr = s0 + q * 4 + r, mc = mt * 16 + lr;
        float vq = expf(gam * cq[r] - 0.0625f * nrm[sr]) * 0.125f;
        float vk = expf(gam * ck[r] - 0.0625f * nrm[64 + sr]) * 0.125f;
        pq[sr * 72 + mc] = f2b(vq);
        ushortT hk = f2b(vk);
        pk[sr * 72 + mc] = hk;
        pkT[mc * 72 + sr] = hk;
      }
    }
  }
  __syncthreads();

  {
    const int d0 = w * 16;
    s8 a0 = *(const s8*)&vT[(d0 + lr) * 72 + q * 8];
    s8 a1 = *(const s8*)&vT[(d0 + lr) * 72 + 32 + q * 8];
    float* outb = KVcT + (size_t)(h * NC_ + c) * DH_ * MF_;
#pragma unroll
    for (int mt = 0; mt < 4; ++mt) {
      s8 b0 = *(const s8*)&pkT[(mt * 16 + lr) * 72 + q * 8];
      s8 b1 = *(const s8*)&pkT[(mt * 16 + lr) * 72 + 32 + q * 8];
      f4 cc = (f4){0.f, 0.f, 0.f, 0.f};
      cc = __builtin_amdgcn_mfma_f32_16x16x32_bf16(a0, b0, cc, 0, 0, 0);
      cc = __builtin_amdgcn_mfma_f32_16x16x32_bf16(a1, b1, cc, 0, 0, 0);
#pragma unroll
      for (int r = 0; r < 4; ++r)
        outb[(size_t)(d0 + q * 4 + r) * MF_ + mt * 16 + lr] = cc[r];
    }
  }
  if (t < 64) {
    float s = 0.f;
#pragma unroll
    for (int seg = 0; seg < 8; ++seg) {
      s8 vv = *(const s8*)&pkT[t * 72 + seg * 8];
#pragma unroll
      for (int j = 0; j < 8; ++j) s += bu2f((ushortT)vv[j]);
    }
    Kc[(size_t)(h * NC_ + c) * MF_ + t] = s;
  }
  for (int i = t; i < 512; i += 256) {
    const int s = i >> 3, seg = i & 7;
    *(s8*)(PQb + (size_t)(c * CT_ + s) * DM_ + h * MF_ + seg * 8) = *(const s8*)&pq[s * 72 + seg * 8];
    *(s8*)(PKb + (size_t)(c * CT_ + s) * DM_ + h * MF_ + seg * 8) = *(const s8*)&pk[s * 72 + seg * 8];
  }
}

__global__ __launch_bounds__(256) void prefix2(float* __restrict__ KVc,
                                               float* __restrict__ Kc) {
  const int h = blockIdx.x, seg = blockIdx.y, t = threadIdx.x;
  if (seg < 16) {
    float* base = KVc + (size_t)h * NC_ * MF_ * DH_ + seg * 256 + t;
    float v[NC_];
#pragma unroll
    for (int c = 0; c < NC_; ++c) v[c] = base[(size_t)c * MF_ * DH_];
    float run = 0.f;
#pragma unroll
    for (int c = 0; c < NC_; ++c) {
      float tmp = v[c];
      base[(size_t)c * MF_ * DH_] = run;
      run += tmp;
    }
  } else if (t < MF_) {
    float* base = Kc + (size_t)h * NC_ * MF_ + t;
    float v[NC_];
#pragma unroll
    for (int c = 0; c < NC_; ++c) v[c] = base[(size_t)c * MF_];
    float run = 0.f;
#pragma unroll
    for (int c = 0; c < NC_; ++c) {
      float tmp = v[c];
      base[(size_t)c * MF_] = run;
      run += tmp;
    }
  }
}

__global__ __launch_bounds__(256) void attn_mfma(const ushortT* __restrict__ PQ,
                                                 const ushortT* __restrict__ PK,
                                                 const ushortT* __restrict__ V,
                                                 const float* __restrict__ KVcT,
                                                 const float* __restrict__ Kc,
                                                 ushortT* __restrict__ Aout) {
  const int cc = blockIdx.x, h = blockIdx.y, t = threadIdx.x;
  const int w = t >> 6, l = t & 63;
  const int lr = l & 15, q = l >> 4;

  __shared__ ushortT pqs[64 * 72];
  __shared__ ushortT pks[64 * 72];
  __shared__ ushortT vts[64 * 72];
  __shared__ ushortT kvs[64 * 72];
  __shared__ ushortT tms[64 * 72];
  __shared__ float dpart[256];
  __shared__ float den[64];

  for (int i = t; i < 512; i += 256) {
    const int s = i >> 3, seg = i & 7;
    *(s8*)&pqs[s * 72 + seg * 8] = *(const s8*)(PQ + (size_t)(cc * CT_ + s) * DM_ + h * MF_ + seg * 8);
    *(s8*)&pks[s * 72 + seg * 8] = *(const s8*)(PK + (size_t)(cc * CT_ + s) * DM_ + h * MF_ + seg * 8);
    s8 av = *(const s8*)(V + (size_t)(cc * CT_ + s) * DM_ + h * DH_ + seg * 8);
#pragma unroll
    for (int j = 0; j < 8; ++j) vts[(seg * 8 + j) * 72 + s] = (ushortT)av[j];
    const float* kr = KVcT + (size_t)((h * NC_ + cc) * DH_ + s) * MF_ + seg * 8;
    f4 g0 = *(const f4*)kr;
    f4 g1 = *(const f4*)(kr + 4);
    u32* p = (u32*)&kvs[s * 72 + seg * 8];
    p[0] = pk2(g0.x, g0.y); p[1] = pk2(g0.z, g0.w);
    p[2] = pk2(g1.x, g1.y); p[3] = pk2(g1.z, g1.w);
  }
  __syncthreads();

  {
    const int s0 = w * 16;
    s8 a0 = *(const s8*)&pqs[(s0 + lr) * 72 + q * 8];
    s8 a1 = *(const s8*)&pqs[(s0 + lr) * 72 + 32 + q * 8];
#pragma unroll
    for (int tb = 0; tb < 4; ++tb) {
      f4 c = (f4){0.f, 0.f, 0.f, 0.f};
      if (tb <= w) {
        s8 b0 = *(const s8*)&pks[(tb * 16 + lr) * 72 + q * 8];
        s8 b1 = *(const s8*)&pks[(tb * 16 + lr) * 72 + 32 + q * 8];
        c = __builtin_amdgcn_mfma_f32_16x16x32_bf16(a0, b0, c, 0, 0, 0);
        c = __builtin_amdgcn_mfma_f32_16x16x32_bf16(a1, b1, c, 0, 0, 0);
      }
#pragma unroll
      for (int r = 0; r < 4; ++r) {
        float v = c[r];
        if (tb == w && lr > q * 4 + r) v = 0.f;
        tms[(s0 + q * 4 + r) * 72 + tb * 16 + lr] = f2b(v);
      }
    }
  }
  __syncthreads();

  {
    const int s = t >> 2, part = t & 3;
    float dp = 0.f;
    const u32* trow = (const u32*)&tms[s * 72 + part * 16];
#pragma unroll
    for (int j = 0; j < 8; ++j) {
      u32 u = trow[j];
      dp += bu2f((ushortT)(u & 0xffffu)) + bu2f((ushortT)(u >> 16));
    }
    const u32* qrow = (const u32*)&pqs[s * 72 + part * 16];
    const f4* kc4 = (const f4*)(Kc + (size_t)(h * NC_ + cc) * MF_ + part * 16);
#pragma unroll
    for (int j = 0; j < 4; ++j) {
      f4 b = kc4[j];
      u32 ua = qrow[2 * j], ub = qrow[2 * j + 1];
      dp += bu2f((ushortT)(ua & 0xffffu)) * b.x + bu2f((ushortT)(ua >> 16)) * b.y +
            bu2f((ushortT)(ub & 0xffffu)) * b.z + bu2f((ushortT)(ub >> 16)) * b.w;
    }
    dpart[t] = dp;
  }
  __syncthreads();
  if (t < 64)
    den[t] = dpart[4 * t] + dpart[4 * t + 1] + dpart[4 * t + 2] + dpart[4 * t + 3] + EPS_;
  __syncthreads();

  {
    const int d0 = w * 16;
    const int drow = d0 + lr;
    s8 akv0 = *(const s8*)&kvs[drow * 72 + q * 8];
    s8 akv1 = *(const s8*)&kvs[drow * 72 + 32 + q * 8];
    s8 av0  = *(const s8*)&vts[drow * 72 + q * 8];
    s8 av1  = *(const s8*)&vts[drow * 72 + 32 + q * 8];
#pragma unroll
    for (int sb = 0; sb < 4; ++sb) {
      const int srow = sb * 16 + lr;
      s8 bq0 = *(const s8*)&pqs[srow * 72 + q * 8];
      s8 bq1 = *(const s8*)&pqs[srow * 72 + 32 + q * 8];
      s8 bt0 = *(const s8*)&tms[srow * 72 + q * 8];
      s8 bt1 = *(const s8*)&tms[srow * 72 + 32 + q * 8];
      f4 c = (f4){0.f, 0.f, 0.f, 0.f};
      c = __builtin_amdgcn_mfma_f32_16x16x32_bf16(akv0, bq0, c, 0, 0, 0);
      c = __builtin_amdgcn_mfma_f32_16x16x32_bf16(akv1, bq1, c, 0, 0, 0);
      c = __builtin_amdgcn_mfma_f32_16x16x32_bf16(av0, bt0, c, 0, 0, 0);
      c = __builtin_amdgcn_mfma_f32_16x16x32_bf16(av1, bt1, c, 0, 0, 0);
      const float inv = 1.f / den[srow];
      u32x2 o;
      o.x = pk2(c[0] * inv, c[1] * inv);
      o.y = pk2(c[2] * inv, c[3] * inv);
      *(u32x2*)(Aout + (size_t)(cc * CT_ + srow) * DM_ + h * DH_ + d0 + q * 4) = o;
    }
  }
}

// ---------------------------------------------------------------- launch
extern "C" void kernel_launch(void* const* d_in, const int* in_sizes, int n_in,
                              void* d_out, int out_size, void* d_ws, size_t ws_size,
                              hipStream_t stream) {
  const float* x    = (const float*)d_in[0];
  const float* Wq   = (const float*)d_in[1];
  const float* Wk   = (const float*)d_in[2];
  const float* Wv   = (const float*)d_in[3];
  const float* Wo   = (const float*)d_in[4];
  const float* W1   = (const float*)d_in[5];
  const float* W2   = (const float*)d_in[6];
  const float* bq   = (const float*)d_in[7];
  const float* bk   = (const float*)d_in[8];
  const float* bv   = (const float*)d_in[9];
  const float* bo   = (const float*)d_in[10];
  const float* b1   = (const float*)d_in[11];
  const float* b2   = (const float*)d_in[12];
  const float* g1   = (const float*)d_in[13];
  const float* be1  = (const float*)d_in[14];
  const float* g2   = (const float*)d_in[15];
  const float* be2  = (const float*)d_in[16];
  const float* omg  = (const float*)d_in[17];
  float* out = (float*)d_out;

  const size_t MB = 1048576;
  float* f    = (float*)d_ws;
  float* cur  = f;                 // [S,DM] fp32
  float* ln1  = f + 1 * MB;
  float* KVcb = f + 2 * MB;        // [H,NC,DH,MF]
  float* Kcb  = f + 3 * MB;
  float* PS   = f + 3 * MB + 16384;

  ushortT* u    = (ushortT*)(f + 8 * MB);
  ushortT* curb = u;
  ushortT* qkb  = u + 1 * MB;      // [3][S,DM]
  ushortT* pqb  = u + 4 * MB;      // fallback only
  ushortT* pkb  = u + 5 * MB;      // fallback only
  ushortT* qbb  = u + 6 * MB;
  ushortT* ln1b = u + 7 * MB;
  ushortT* ffb  = u + 8 * MB;      // [S,DFF]
  ushortT* wb   = u + 12 * MB;
  ushortT* omgTb = wb + 2 * LSW_;

  tcast_all<<<10248, 256, 0, stream>>>(x, Wq, Wk, Wv, Wo, W1, W2, omg,
                                       cur, curb, wb, omgTb);

  const dim3 gQKV(DM_ / 64, S_ / 64, 3);
  const dim3 gFF1(DFF_ / 64, S_ / 64, 1);
  const dim3 gWo(DM_ / 64, S_ / 64, 2);
  const dim3 gW2(DM_ / 64, S_ / 64, 4);
  const dim3 gAttn(NC_, H_);
  const dim3 gPre(H_, 17);

  for (int l = 0; l < L_; ++l) {
    const ushortT* wl = wb + (size_t)l * LSW_;
    const size_t bo512 = (size_t)l * DM_;
    const size_t boFF = (size_t)l * DFF_;

    mgemm<false, false, true><<<gQKV, 256, 0, stream>>>(
        curb, wl, bq + bo512, bk + bo512, bv + bo512, nullptr, nullptr, qkb, DM_, DM_);

    {
      const ushortT* qkvp = qkb;
      const ushortT* omgTl = omgTb + (size_t)l * DH_ * MF_;
      float* kvp = KVcb; float* kcp = Kcb; ushortT* aoutp = qbb;
      void* cargs[] = {(void*)&qkvp, (void*)&omgTl, (void*)&kvp, (void*)&kcp, (void*)&aoutp};
      hipError_t ce = hipLaunchCooperativeKernel((const void*)attn_all,
                                                 dim3(NC_ * H_), dim3(256),
                                                 cargs, 0, stream);
      if (ce != hipSuccess) {  // fallback: non-cooperative 3-kernel path (same math)
        favor_cs<<<gAttn, 256, 0, stream>>>(qkb, omgTl, pqb, pkb, KVcb, Kcb);
        prefix2<<<gPre, 256, 0, stream>>>(KVcb, Kcb);
        attn_mfma<<<gAttn, 256, 0, stream>>>(pqb, pkb, qkb + 2 * (size_t)S_ * DM_,
                                             KVcb, Kcb, qbb);
      }
    }

    mgemm_part<<<gWo, 256, 0, stream>>>(qbb, wl + WOOFF_, PS, DM_, DM_, 256);
    redln<<<S_, 256, 0, stream>>>(PS, 2, bo + bo512, cur, g1 + bo512, be1 + bo512, ln1, ln1b);

    mgemm<true, false, true><<<gFF1, 256, 0, stream>>>(
        ln1b, wl + W1OFF_, b1 + boFF, nullptr, nullptr, nullptr, nullptr, ffb, DM_, DFF_);

    mgemm_part<<<gW2, 256, 0, stream>>>(ffb, wl + W2OFF_, PS, DFF_, DM_, 512);
    const bool last = (l == L_ - 1);
    redln<<<S_, 256, 0, stream>>>(PS, 4, b2 + bo512, ln1, g2 + bo512, be2 + bo512,
                                  last ? out : cur, last ? nullptr : curb);
  }
}

// Round 7
// 264.818 us; speedup vs baseline: 2.0334x; 2.0334x over previous
//
#include <hip/hip_runtime.h>
#include <hip/hip_bf16.h>

#define S_  2048
#define DM_ 512
#define H_  8
#define DH_ 64
#define MF_ 64
#define DFF_ 2048
#define L_  2
#define CT_ 64
#define NC_ (S_ / CT_)
#define EPS_ 1e-6f
#define LN_EPS_ 1e-5f

#define LSW_   3145728
#define W1OFF_ 1048576
#define W2OFF_ 2097152
#define WOOFF_ 786432

typedef unsigned short ushortT;
typedef unsigned int u32;
typedef float f4 __attribute__((ext_vector_type(4)));
typedef short s8 __attribute__((ext_vector_type(8)));
typedef u32 u32x2 __attribute__((ext_vector_type(2)));

__device__ __forceinline__ ushortT f2b(float f) {
  union { float f; unsigned u; } v; v.f = f;
  unsigned r = v.u + 0x7fffu + ((v.u >> 16) & 1u);  // RNE
  return (ushortT)(r >> 16);
}
__device__ __forceinline__ float bu2f(ushortT h) {
  union { unsigned u; float f; } v; v.u = ((unsigned)h) << 16; return v.f;
}
__device__ __forceinline__ u32 pk2(float a, float b) {
  return (u32)f2b(a) | ((u32)f2b(b) << 16);
}

// ---------------------------------------------------------------- fused setup
// flat grid: [0,2048) QKVO transpose, [2048,4096) W1, [4096,6144) W2,
// [6144,6152) omega, [6152,10248) copy_in
__global__ __launch_bounds__(256) void tcast_all(
    const float* __restrict__ x,
    const float* __restrict__ Wq, const float* __restrict__ Wk,
    const float* __restrict__ Wv, const float* __restrict__ Wo,
    const float* __restrict__ W1, const float* __restrict__ W2,
    const float* __restrict__ omg,
    float* __restrict__ cur, ushortT* __restrict__ curb,
    ushortT* __restrict__ wb, ushortT* __restrict__ omgTb) {
  const int bid = blockIdx.x;
  const int t = threadIdx.x;
  if (bid >= 6152) {  // copy_in
    const int i = (bid - 6152) * 256 + t;
    float v = x[i];
    cur[i] = v;
    curb[i] = f2b(v);
    return;
  }
  __shared__ ushortT tile[32][33];
  const float* src; ushortT* dst; int K, N, bx, by;
  if (bid < 2048) {
    const int z = bid >> 8, widx = z & 3, lay = z >> 2;
    const float* s4[4] = {Wq, Wk, Wv, Wo};
    src = s4[widx] + (size_t)lay * DM_ * DM_;
    dst = wb + (size_t)lay * LSW_ + (size_t)widx * DM_ * DM_;
    K = DM_; N = DM_; bx = bid & 15; by = (bid >> 4) & 15;
  } else if (bid < 4096) {
    const int r = bid - 2048;
    const int lay = r >> 10;
    src = W1 + (size_t)lay * DM_ * DFF_;
    dst = wb + (size_t)lay * LSW_ + W1OFF_;
    K = DM_; N = DFF_; bx = r & 63; by = (r >> 6) & 15;
  } else if (bid < 6144) {
    const int r = bid - 4096;
    const int lay = r >> 10;
    src = W2 + (size_t)lay * DFF_ * DM_;
    dst = wb + (size_t)lay * LSW_ + W2OFF_;
    K = DFF_; N = DM_; bx = r & 15; by = (r >> 4) & 63;
  } else {
    const int r = bid - 6144;
    const int lay = r >> 2;
    src = omg + (size_t)lay * DH_ * MF_;
    dst = omgTb + (size_t)lay * DH_ * MF_;
    K = DH_; N = MF_; bx = r & 1; by = (r >> 1) & 1;
  }
  const int cc = t & 31, r0 = t >> 5;
  const int n0 = bx * 32, k0 = by * 32;
#pragma unroll
  for (int i = 0; i < 4; ++i) {
    int r = r0 + 8 * i;
    tile[r][cc] = f2b(src[(size_t)(k0 + r) * N + n0 + cc]);
  }
  __syncthreads();
#pragma unroll
  for (int i = 0; i < 4; ++i) {
    int r = r0 + 8 * i;
    dst[(size_t)(n0 + r) * K + k0 + cc] = tile[cc][r];
  }
}

// ---------------------------------------------------------------- MFMA GEMM (full-K)
template<bool RELU, bool HAS_RES, bool OUT_BF16>
__global__ __launch_bounds__(256) void mgemm(
    const ushortT* __restrict__ A, const ushortT* __restrict__ Wt,
    const float* __restrict__ bq_, const float* __restrict__ bk_,
    const float* __restrict__ bv_, const float* __restrict__ Res,
    float* __restrict__ Cf, ushortT* __restrict__ Cb, int K, int N) {
  __shared__ ushortT sA[2][2048];
  __shared__ ushortT sB[2][2048];
  const int t = threadIdx.x;
  const int w = t >> 6, l = t & 63;
  const int wm = w >> 1, wn = w & 1;
  const int n0 = blockIdx.x * 64, m0 = blockIdx.y * 64;
  const int z = blockIdx.z;
  const ushortT* Wz = Wt + (size_t)z * K * N;
  const float* bias = (z == 0) ? bq_ : (z == 1 ? bk_ : bv_);

  const int rs = w * 16 + (l >> 2);
  const int qs = (l & 3) ^ ((rs >> 1) & 3);
  const ushortT* gA = A  + (size_t)(m0 + rs) * K + qs * 8;
  const ushortT* gB = Wz + (size_t)(n0 + rs) * K + qs * 8;

  const int Ra = wm * 32 + (l & 15);
  const int Rb = wn * 32 + (l & 15);
  const int qq = l >> 4;
  const int aoff = (Ra * 4 + (qq ^ ((Ra >> 1) & 3))) * 8;
  const int boff = (Rb * 4 + (qq ^ ((Rb >> 1) & 3))) * 8;

  f4 acc[2][2];
#pragma unroll
  for (int i = 0; i < 2; ++i)
#pragma unroll
    for (int j = 0; j < 2; ++j) acc[i][j] = (f4){0.f, 0.f, 0.f, 0.f};

  auto stage = [&](int buf, int ko) {
    __builtin_amdgcn_global_load_lds(
        (const __attribute__((address_space(1))) void*)(gA + ko),
        (__attribute__((address_space(3))) void*)(&sA[buf][w * 512]), 16, 0, 0);
    __builtin_amdgcn_global_load_lds(
        (const __attribute__((address_space(1))) void*)(gB + ko),
        (__attribute__((address_space(3))) void*)(&sB[buf][w * 512]), 16, 0, 0);
  };

  stage(0, 0);
  const int nk = K >> 5;
  for (int ks = 0; ks < nk; ++ks) {
    __syncthreads();
    if (ks + 1 < nk) stage((ks + 1) & 1, (ks + 1) * 32);
    const ushortT* pa = sA[ks & 1];
    const ushortT* pb = sB[ks & 1];
    s8 a0 = *(const s8*)(pa + aoff);
    s8 a1 = *(const s8*)(pa + aoff + 512);
    s8 b0 = *(const s8*)(pb + boff);
    s8 b1 = *(const s8*)(pb + boff + 512);
    acc[0][0] = __builtin_amdgcn_mfma_f32_16x16x32_bf16(a0, b0, acc[0][0], 0, 0, 0);
    acc[0][1] = __builtin_amdgcn_mfma_f32_16x16x32_bf16(a0, b1, acc[0][1], 0, 0, 0);
    acc[1][0] = __builtin_amdgcn_mfma_f32_16x16x32_bf16(a1, b0, acc[1][0], 0, 0, 0);
    acc[1][1] = __builtin_amdgcn_mfma_f32_16x16x32_bf16(a1, b1, acc[1][1], 0, 0, 0);
  }

  const size_t outz = (size_t)z * S_ * N;
  const int colb = n0 + wn * 32 + (l & 15);
  const int rowb = m0 + wm * 32 + ((l >> 4) << 2);
#pragma unroll
  for (int mt = 0; mt < 2; ++mt) {
#pragma unroll
    for (int nt = 0; nt < 2; ++nt) {
      const int c = colb + nt * 16;
      const float bv = bias[c];
#pragma unroll
      for (int r = 0; r < 4; ++r) {
        const int rr = rowb + mt * 16 + r;
        float v = acc[mt][nt][r] + bv;
        if (HAS_RES) v += Res[(size_t)rr * N + c];
        if (RELU) v = fmaxf(v, 0.f);
        if (OUT_BF16) Cb[outz + (size_t)rr * N + c] = f2b(v);
        else          Cf[outz + (size_t)rr * N + c] = v;
      }
    }
  }
}

// ---------------------------------------------------------------- MFMA GEMM partial (split-K)
__global__ __launch_bounds__(256) void mgemm_part(
    const ushortT* __restrict__ A, const ushortT* __restrict__ Wt,
    float* __restrict__ PS, int K, int N, int KS) {
  __shared__ ushortT sA[2][2048];
  __shared__ ushortT sB[2][2048];
  const int t = threadIdx.x;
  const int w = t >> 6, l = t & 63;
  const int wm = w >> 1, wn = w & 1;
  const int n0 = blockIdx.x * 64, m0 = blockIdx.y * 64;
  const int z = blockIdx.z;

  const int rs = w * 16 + (l >> 2);
  const int qs = (l & 3) ^ ((rs >> 1) & 3);
  const ushortT* gA = A  + (size_t)(m0 + rs) * K + z * KS + qs * 8;
  const ushortT* gB = Wt + (size_t)(n0 + rs) * K + z * KS + qs * 8;

  const int Ra = wm * 32 + (l & 15);
  const int Rb = wn * 32 + (l & 15);
  const int qq = l >> 4;
  const int aoff = (Ra * 4 + (qq ^ ((Ra >> 1) & 3))) * 8;
  const int boff = (Rb * 4 + (qq ^ ((Rb >> 1) & 3))) * 8;

  f4 acc[2][2];
#pragma unroll
  for (int i = 0; i < 2; ++i)
#pragma unroll
    for (int j = 0; j < 2; ++j) acc[i][j] = (f4){0.f, 0.f, 0.f, 0.f};

  auto stage = [&](int buf, int ko) {
    __builtin_amdgcn_global_load_lds(
        (const __attribute__((address_space(1))) void*)(gA + ko),
        (__attribute__((address_space(3))) void*)(&sA[buf][w * 512]), 16, 0, 0);
    __builtin_amdgcn_global_load_lds(
        (const __attribute__((address_space(1))) void*)(gB + ko),
        (__attribute__((address_space(3))) void*)(&sB[buf][w * 512]), 16, 0, 0);
  };

  stage(0, 0);
  const int nk = KS >> 5;
  for (int ks = 0; ks < nk; ++ks) {
    __syncthreads();
    if (ks + 1 < nk) stage((ks + 1) & 1, (ks + 1) * 32);
    const ushortT* pa = sA[ks & 1];
    const ushortT* pb = sB[ks & 1];
    s8 a0 = *(const s8*)(pa + aoff);
    s8 a1 = *(const s8*)(pa + aoff + 512);
    s8 b0 = *(const s8*)(pb + boff);
    s8 b1 = *(const s8*)(pb + boff + 512);
    acc[0][0] = __builtin_amdgcn_mfma_f32_16x16x32_bf16(a0, b0, acc[0][0], 0, 0, 0);
    acc[0][1] = __builtin_amdgcn_mfma_f32_16x16x32_bf16(a0, b1, acc[0][1], 0, 0, 0);
    acc[1][0] = __builtin_amdgcn_mfma_f32_16x16x32_bf16(a1, b0, acc[1][0], 0, 0, 0);
    acc[1][1] = __builtin_amdgcn_mfma_f32_16x16x32_bf16(a1, b1, acc[1][1], 0, 0, 0);
  }

  float* out = PS + (size_t)z * S_ * N;
  const int colb = n0 + wn * 32 + (l & 15);
  const int rowb = m0 + wm * 32 + ((l >> 4) << 2);
#pragma unroll
  for (int mt = 0; mt < 2; ++mt) {
#pragma unroll
    for (int nt = 0; nt < 2; ++nt) {
      const int c = colb + nt * 16;
#pragma unroll
      for (int r = 0; r < 4; ++r)
        out[(size_t)(rowb + mt * 16 + r) * N + c] = acc[mt][nt][r];
    }
  }
}

// ---------------------------------------------------------------- reduce splits + bias + res + LN
__global__ __launch_bounds__(256) void redln(const float* __restrict__ PS, int nsplit,
                                             const float* __restrict__ bias,
                                             const float* __restrict__ res,
                                             const float* __restrict__ g,
                                             const float* __restrict__ be,
                                             float* __restrict__ outF,
                                             ushortT* __restrict__ outB) {
  const int s = blockIdx.x, t = threadIdx.x;
  float v0 = bias[t] + res[(size_t)s * DM_ + t];
  float v1 = bias[t + 256] + res[(size_t)s * DM_ + 256 + t];
  for (int z = 0; z < nsplit; ++z) {
    const float* p = PS + (size_t)z * S_ * DM_ + (size_t)s * DM_;
    v0 += p[t];
    v1 += p[256 + t];
  }
  float sum = v0 + v1, sq = v0 * v0 + v1 * v1;
  for (int off = 32; off > 0; off >>= 1) {
    sum += __shfl_down(sum, off);
    sq += __shfl_down(sq, off);
  }
  __shared__ float ssum[4], ssq[4];
  __shared__ float smean, srstd;
  const int w = t >> 6;
  if ((t & 63) == 0) { ssum[w] = sum; ssq[w] = sq; }
  __syncthreads();
  if (t == 0) {
    float S1 = ssum[0] + ssum[1] + ssum[2] + ssum[3];
    float S2 = ssq[0] + ssq[1] + ssq[2] + ssq[3];
    float mu = S1 / DM_;
    smean = mu;
    srstd = rsqrtf(S2 / DM_ - mu * mu + LN_EPS_);
  }
  __syncthreads();
  const float mu = smean, rs = srstd;
  float o0 = (v0 - mu) * rs * g[t] + be[t];
  float o1 = (v1 - mu) * rs * g[256 + t] + be[256 + t];
  outF[(size_t)s * DM_ + t] = o0;
  outF[(size_t)s * DM_ + 256 + t] = o1;
  if (outB) {
    outB[(size_t)s * DM_ + t] = f2b(o0);
    outB[(size_t)s * DM_ + 256 + t] = f2b(o1);
  }
}

// ---------------------------------------------------------------- FAVOR+ + chunk sums (fused, MFMA)
__global__ __launch_bounds__(256) void favor_cs(const ushortT* __restrict__ qkv,
                                                const ushortT* __restrict__ omgT,
                                                ushortT* __restrict__ PQb,
                                                ushortT* __restrict__ PKb,
                                                float* __restrict__ KVcT,
                                                float* __restrict__ Kc) {
  const int c = blockIdx.x, h = blockIdx.y, t = threadIdx.x;
  const int w = t >> 6, l = t & 63, lr = l & 15, q = l >> 4;
  __shared__ ushortT xq[64 * 72], xk[64 * 72], vT[64 * 72], omT[64 * 72];
  __shared__ ushortT pq[64 * 72], pk[64 * 72], pkT[64 * 72];
  __shared__ float nrm[128];

  const ushortT* qg = qkv + (size_t)(c * CT_) * DM_ + h * DH_;
  const ushortT* kg = qg + (size_t)S_ * DM_;
  const ushortT* vg = kg + (size_t)S_ * DM_;

  for (int i = t; i < 512; i += 256) {
    const int s = i >> 3, seg = i & 7;
    *(s8*)&xq[s * 72 + seg * 8] = *(const s8*)(qg + (size_t)s * DM_ + seg * 8);
    *(s8*)&xk[s * 72 + seg * 8] = *(const s8*)(kg + (size_t)s * DM_ + seg * 8);
    s8 av = *(const s8*)(vg + (size_t)s * DM_ + seg * 8);
#pragma unroll
    for (int j = 0; j < 8; ++j) vT[(seg * 8 + j) * 72 + s] = (ushortT)av[j];
    *(s8*)&omT[s * 72 + seg * 8] = *(const s8*)(omgT + s * 64 + seg * 8);
  }
  __syncthreads();

  if (t < 128) {
    const ushortT* src = (t < 64) ? xq : xk;
    const int s = t & 63;
    float a = 0.f;
#pragma unroll
    for (int seg = 0; seg < 8; ++seg) {
      s8 vv = *(const s8*)(src + s * 72 + seg * 8);
#pragma unroll
      for (int j = 0; j < 8; ++j) {
        float f = bu2f((ushortT)vv[j]);
        a += f * f;
      }
    }
    nrm[t] = a;
  }
  __syncthreads();

  {
    const float gam = 0.35355339059327373f;
    const int s0 = w * 16;
    s8 aq0 = *(const s8*)&xq[(s0 + lr) * 72 + q * 8];
    s8 aq1 = *(const s8*)&xq[(s0 + lr) * 72 + 32 + q * 8];
    s8 ak0 = *(const s8*)&xk[(s0 + lr) * 72 + q * 8];
    s8 ak1 = *(const s8*)&xk[(s0 + lr) * 72 + 32 + q * 8];
#pragma unroll
    for (int mt = 0; mt < 4; ++mt) {
      s8 b0 = *(const s8*)&omT[(mt * 16 + lr) * 72 + q * 8];
      s8 b1 = *(const s8*)&omT[(mt * 16 + lr) * 72 + 32 + q * 8];
      f4 cq = (f4){0.f, 0.f, 0.f, 0.f}, ck = (f4){0.f, 0.f, 0.f, 0.f};
      cq = __builtin_amdgcn_mfma_f32_16x16x32_bf16(aq0, b0, cq, 0, 0, 0);
      cq = __builtin_amdgcn_mfma_f32_16x16x32_bf16(aq1, b1, cq, 0, 0, 0);
      ck = __builtin_amdgcn_mfma_f32_16x16x32_bf16(ak0, b0, ck, 0, 0, 0);
      ck = __builtin_amdgcn_mfma_f32_16x16x32_bf16(ak1, b1, ck, 0, 0, 0);
#pragma unroll
      for (int r = 0; r < 4; ++r) {
        const int sr = s0 + q * 4 + r, mc = mt * 16 + lr;
        float vq = expf(gam * cq[r] - 0.0625f * nrm[sr]) * 0.125f;
        float vk = expf(gam * ck[r] - 0.0625f * nrm[64 + sr]) * 0.125f;
        pq[sr * 72 + mc] = f2b(vq);
        ushortT hk = f2b(vk);
        pk[sr * 72 + mc] = hk;
        pkT[mc * 72 + sr] = hk;
      }
    }
  }
  __syncthreads();

  {
    const int d0 = w * 16;
    s8 a0 = *(const s8*)&vT[(d0 + lr) * 72 + q * 8];
    s8 a1 = *(const s8*)&vT[(d0 + lr) * 72 + 32 + q * 8];
    float* outb = KVcT + (size_t)(h * NC_ + c) * DH_ * MF_;
#pragma unroll
    for (int mt = 0; mt < 4; ++mt) {
      s8 b0 = *(const s8*)&pkT[(mt * 16 + lr) * 72 + q * 8];
      s8 b1 = *(const s8*)&pkT[(mt * 16 + lr) * 72 + 32 + q * 8];
      f4 cc = (f4){0.f, 0.f, 0.f, 0.f};
      cc = __builtin_amdgcn_mfma_f32_16x16x32_bf16(a0, b0, cc, 0, 0, 0);
      cc = __builtin_amdgcn_mfma_f32_16x16x32_bf16(a1, b1, cc, 0, 0, 0);
#pragma unroll
      for (int r = 0; r < 4; ++r)
        outb[(size_t)(d0 + q * 4 + r) * MF_ + mt * 16 + lr] = cc[r];
    }
  }
  if (t < 64) {
    float s = 0.f;
#pragma unroll
    for (int seg = 0; seg < 8; ++seg) {
      s8 vv = *(const s8*)&pkT[t * 72 + seg * 8];
#pragma unroll
      for (int j = 0; j < 8; ++j) s += bu2f((ushortT)vv[j]);
    }
    Kc[(size_t)(h * NC_ + c) * MF_ + t] = s;
  }
  for (int i = t; i < 512; i += 256) {
    const int s = i >> 3, seg = i & 7;
    *(s8*)(PQb + (size_t)(c * CT_ + s) * DM_ + h * MF_ + seg * 8) = *(const s8*)&pq[s * 72 + seg * 8];
    *(s8*)(PKb + (size_t)(c * CT_ + s) * DM_ + h * MF_ + seg * 8) = *(const s8*)&pk[s * 72 + seg * 8];
  }
}

// ---------------------------------------------------------------- attention out (MFMA, inline prefix)
// Each block (c,h) computes exclusive prefix sum over chunks c' < c directly
// from the per-chunk sums in global (L2-resident, same add order as a serial scan).
__global__ __launch_bounds__(256) void attn_pfx(const ushortT* __restrict__ PQ,
                                                const ushortT* __restrict__ PK,
                                                const ushortT* __restrict__ V,
                                                const float* __restrict__ KVcT,
                                                const float* __restrict__ Kc,
                                                ushortT* __restrict__ Aout) {
  const int cc = blockIdx.x, h = blockIdx.y, t = threadIdx.x;
  const int w = t >> 6, l = t & 63;
  const int lr = l & 15, q = l >> 4;

  __shared__ ushortT pqs[64 * 72];
  __shared__ ushortT pks[64 * 72];
  __shared__ ushortT vts[64 * 72];
  __shared__ ushortT kvs[64 * 72];
  __shared__ ushortT tms[64 * 72];
  __shared__ float dpart[256];
  __shared__ float den[64];
  __shared__ float kcs[64];

  // per-thread jobs for the kv tile: i = t, t+256
  const int s0j = t >> 3, seg0 = t & 7;          // job 0
  const int s1j = (t + 256) >> 3, seg1 = t & 7;  // job 1 (same seg)
  float acc0[8], acc1[8];
#pragma unroll
  for (int j = 0; j < 8; ++j) { acc0[j] = 0.f; acc1[j] = 0.f; }

  // inline exclusive prefix of KVcT over chunks < cc (independent f4 loads, L2)
  const float* kvbase = KVcT + (size_t)(h * NC_) * DH_ * MF_;
  for (int cp = 0; cp < cc; ++cp) {
    const float* kr = kvbase + (size_t)cp * DH_ * MF_;
    f4 a0 = *(const f4*)(kr + s0j * MF_ + seg0 * 8);
    f4 a1 = *(const f4*)(kr + s0j * MF_ + seg0 * 8 + 4);
    f4 b0 = *(const f4*)(kr + s1j * MF_ + seg1 * 8);
    f4 b1 = *(const f4*)(kr + s1j * MF_ + seg1 * 8 + 4);
    acc0[0] += a0.x; acc0[1] += a0.y; acc0[2] += a0.z; acc0[3] += a0.w;
    acc0[4] += a1.x; acc0[5] += a1.y; acc0[6] += a1.z; acc0[7] += a1.w;
    acc1[0] += b0.x; acc1[1] += b0.y; acc1[2] += b0.z; acc1[3] += b0.w;
    acc1[4] += b1.x; acc1[5] += b1.y; acc1[6] += b1.z; acc1[7] += b1.w;
  }
  {
    u32* p0 = (u32*)&kvs[s0j * 72 + seg0 * 8];
    p0[0] = pk2(acc0[0], acc0[1]); p0[1] = pk2(acc0[2], acc0[3]);
    p0[2] = pk2(acc0[4], acc0[5]); p0[3] = pk2(acc0[6], acc0[7]);
    u32* p1 = (u32*)&kvs[s1j * 72 + seg1 * 8];
    p1[0] = pk2(acc1[0], acc1[1]); p1[1] = pk2(acc1[2], acc1[3]);
    p1[2] = pk2(acc1[4], acc1[5]); p1[3] = pk2(acc1[6], acc1[7]);
  }
  // inline exclusive prefix of Kc
  if (t < 64) {
    float s = 0.f;
    for (int cp = 0; cp < cc; ++cp) s += Kc[(size_t)(h * NC_ + cp) * MF_ + t];
    kcs[t] = s;
  }

  for (int i = t; i < 512; i += 256) {
    const int s = i >> 3, seg = i & 7;
    *(s8*)&pqs[s * 72 + seg * 8] = *(const s8*)(PQ + (size_t)(cc * CT_ + s) * DM_ + h * MF_ + seg * 8);
    *(s8*)&pks[s * 72 + seg * 8] = *(const s8*)(PK + (size_t)(cc * CT_ + s) * DM_ + h * MF_ + seg * 8);
    s8 av = *(const s8*)(V + (size_t)(cc * CT_ + s) * DM_ + h * DH_ + seg * 8);
#pragma unroll
    for (int j = 0; j < 8; ++j) vts[(seg * 8 + j) * 72 + s] = (ushortT)av[j];
  }
  __syncthreads();

  // Tm = PQ @ PK^T, tril
  {
    const int s0 = w * 16;
    s8 a0 = *(const s8*)&pqs[(s0 + lr) * 72 + q * 8];
    s8 a1 = *(const s8*)&pqs[(s0 + lr) * 72 + 32 + q * 8];
#pragma unroll
    for (int tb = 0; tb < 4; ++tb) {
      f4 c = (f4){0.f, 0.f, 0.f, 0.f};
      if (tb <= w) {
        s8 b0 = *(const s8*)&pks[(tb * 16 + lr) * 72 + q * 8];
        s8 b1 = *(const s8*)&pks[(tb * 16 + lr) * 72 + 32 + q * 8];
        c = __builtin_amdgcn_mfma_f32_16x16x32_bf16(a0, b0, c, 0, 0, 0);
        c = __builtin_amdgcn_mfma_f32_16x16x32_bf16(a1, b1, c, 0, 0, 0);
      }
#pragma unroll
      for (int r = 0; r < 4; ++r) {
        float v = c[r];
        if (tb == w && lr > q * 4 + r) v = 0.f;
        tms[(s0 + q * 4 + r) * 72 + tb * 16 + lr] = f2b(v);
      }
    }
  }
  __syncthreads();

  // den
  {
    const int s = t >> 2, part = t & 3;
    float dp = 0.f;
    const u32* trow = (const u32*)&tms[s * 72 + part * 16];
#pragma unroll
    for (int j = 0; j < 8; ++j) {
      u32 u = trow[j];
      dp += bu2f((ushortT)(u & 0xffffu)) + bu2f((ushortT)(u >> 16));
    }
    const u32* qrow = (const u32*)&pqs[s * 72 + part * 16];
    const f4* kc4 = (const f4*)(kcs + part * 16);
#pragma unroll
    for (int j = 0; j < 4; ++j) {
      f4 b = kc4[j];
      u32 ua = qrow[2 * j], ub = qrow[2 * j + 1];
      dp += bu2f((ushortT)(ua & 0xffffu)) * b.x + bu2f((ushortT)(ua >> 16)) * b.y +
            bu2f((ushortT)(ub & 0xffffu)) * b.z + bu2f((ushortT)(ub >> 16)) * b.w;
    }
    dpart[t] = dp;
  }
  __syncthreads();
  if (t < 64)
    den[t] = dpart[4 * t] + dpart[4 * t + 1] + dpart[4 * t + 2] + dpart[4 * t + 3] + EPS_;
  __syncthreads();

  // numT + divide + store
  {
    const int d0 = w * 16;
    const int drow = d0 + lr;
    s8 akv0 = *(const s8*)&kvs[drow * 72 + q * 8];
    s8 akv1 = *(const s8*)&kvs[drow * 72 + 32 + q * 8];
    s8 av0  = *(const s8*)&vts[drow * 72 + q * 8];
    s8 av1  = *(const s8*)&vts[drow * 72 + 32 + q * 8];
#pragma unroll
    for (int sb = 0; sb < 4; ++sb) {
      const int srow = sb * 16 + lr;
      s8 bq0 = *(const s8*)&pqs[srow * 72 + q * 8];
      s8 bq1 = *(const s8*)&pqs[srow * 72 + 32 + q * 8];
      s8 bt0 = *(const s8*)&tms[srow * 72 + q * 8];
      s8 bt1 = *(const s8*)&tms[srow * 72 + 32 + q * 8];
      f4 c = (f4){0.f, 0.f, 0.f, 0.f};
      c = __builtin_amdgcn_mfma_f32_16x16x32_bf16(akv0, bq0, c, 0, 0, 0);
      c = __builtin_amdgcn_mfma_f32_16x16x32_bf16(akv1, bq1, c, 0, 0, 0);
      c = __builtin_amdgcn_mfma_f32_16x16x32_bf16(av0, bt0, c, 0, 0, 0);
      c = __builtin_amdgcn_mfma_f32_16x16x32_bf16(av1, bt1, c, 0, 0, 0);
      const float inv = 1.f / den[srow];
      u32x2 o;
      o.x = pk2(c[0] * inv, c[1] * inv);
      o.y = pk2(c[2] * inv, c[3] * inv);
      *(u32x2*)(Aout + (size_t)(cc * CT_ + srow) * DM_ + h * DH_ + d0 + q * 4) = o;
    }
  }
}

// ---------------------------------------------------------------- launch
extern "C" void kernel_launch(void* const* d_in, const int* in_sizes, int n_in,
                              void* d_out, int out_size, void* d_ws, size_t ws_size,
                              hipStream_t stream) {
  const float* x    = (const float*)d_in[0];
  const float* Wq   = (const float*)d_in[1];
  const float* Wk   = (const float*)d_in[2];
  const float* Wv   = (const float*)d_in[3];
  const float* Wo   = (const float*)d_in[4];
  const float* W1   = (const float*)d_in[5];
  const float* W2   = (const float*)d_in[6];
  const float* bq   = (const float*)d_in[7];
  const float* bk   = (const float*)d_in[8];
  const float* bv   = (const float*)d_in[9];
  const float* bo   = (const float*)d_in[10];
  const float* b1   = (const float*)d_in[11];
  const float* b2   = (const float*)d_in[12];
  const float* g1   = (const float*)d_in[13];
  const float* be1  = (const float*)d_in[14];
  const float* g2   = (const float*)d_in[15];
  const float* be2  = (const float*)d_in[16];
  const float* omg  = (const float*)d_in[17];
  float* out = (float*)d_out;

  const size_t MB = 1048576;
  float* f    = (float*)d_ws;
  float* cur  = f;
  float* ln1  = f + 1 * MB;
  float* KVcb = f + 2 * MB;        // [H,NC,DH,MF] per-chunk sums (not prefixed)
  float* Kcb  = f + 3 * MB;
  float* PS   = f + 3 * MB + 16384;

  ushortT* u    = (ushortT*)(f + 8 * MB);
  ushortT* curb = u;
  ushortT* qkb  = u + 1 * MB;      // [3][S,DM]
  ushortT* pqb  = u + 4 * MB;
  ushortT* pkb  = u + 5 * MB;
  ushortT* qbb  = u + 6 * MB;
  ushortT* ln1b = u + 7 * MB;
  ushortT* ffb  = u + 8 * MB;      // [S,DFF]
  ushortT* wb   = u + 12 * MB;
  ushortT* omgTb = wb + 2 * LSW_;

  tcast_all<<<10248, 256, 0, stream>>>(x, Wq, Wk, Wv, Wo, W1, W2, omg,
                                       cur, curb, wb, omgTb);

  const dim3 gQKV(DM_ / 64, S_ / 64, 3);
  const dim3 gFF1(DFF_ / 64, S_ / 64, 1);
  const dim3 gWo(DM_ / 64, S_ / 64, 2);
  const dim3 gW2(DM_ / 64, S_ / 64, 4);
  const dim3 gAttn(NC_, H_);

  for (int l = 0; l < L_; ++l) {
    const ushortT* wl = wb + (size_t)l * LSW_;
    const size_t bo512 = (size_t)l * DM_;
    const size_t boFF = (size_t)l * DFF_;

    mgemm<false, false, true><<<gQKV, 256, 0, stream>>>(
        curb, wl, bq + bo512, bk + bo512, bv + bo512, nullptr, nullptr, qkb, DM_, DM_);

    favor_cs<<<gAttn, 256, 0, stream>>>(qkb, omgTb + (size_t)l * DH_ * MF_,
                                        pqb, pkb, KVcb, Kcb);
    attn_pfx<<<gAttn, 256, 0, stream>>>(pqb, pkb, qkb + 2 * (size_t)S_ * DM_,
                                        KVcb, Kcb, qbb);

    mgemm_part<<<gWo, 256, 0, stream>>>(qbb, wl + WOOFF_, PS, DM_, DM_, 256);
    redln<<<S_, 256, 0, stream>>>(PS, 2, bo + bo512, cur, g1 + bo512, be1 + bo512, ln1, ln1b);

    mgemm<true, false, true><<<gFF1, 256, 0, stream>>>(
        ln1b, wl + W1OFF_, b1 + boFF, nullptr, nullptr, nullptr, nullptr, ffb, DM_, DFF_);

    mgemm_part<<<gW2, 256, 0, stream>>>(ffb, wl + W2OFF_, PS, DFF_, DM_, 512);
    const bool last = (l == L_ - 1);
    redln<<<S_, 256, 0, stream>>>(PS, 4, b2 + bo512, ln1, g2 + bo512, be2 + bo512,
                                  last ? out : cur, last ? nullptr : curb);
  }
}